// Round 13
// baseline (791.187 us; speedup 1.0000x reference)
//
#include <hip/hip_runtime.h>

// LSTM anomaly detector: B=4096, T=512, I=3, H=64 (4H=256 gates)
// R15 = R14 math at ROWS=8, 2 independent blocks/CU (grid 512):
//  - M=16 tiles with rows 0-7 real. MFMA cost is per-wave (16/wave, same),
//    so halving rows does NOT double per-CU MFMA-adjusted work; the matrix
//    pipe (85% idle) absorbs the 2x.
//  - Cross-lane activation split keeps VALU/trans work constant: after each
//    gate's preact merge, shfl_xor(32) sends rows{2,3}/{6,7} preacts from
//    q0/q1 to q2/q3 lanes. Each lane owns 2 cells (q0:{0,1} q1:{4,5}
//    q2:{2,3} q3:{6,7}): 20 trans/wave (vs 40), own c-state, own h writes.
//    Finished fp32 values move lanes - per-cell arithmetic bit-identical
//    to R14 => absmax must stay exactly 2^-10.
//  - Independent barriers: one block's stalls (barrier, ds_read ~120cy,
//    MFMA latency) hide under the other block's issue. (R4 failed at 2x
//    work; R7 failed with lockstep same-block waves; this is the missing
//    quadrant: 2 independent blocks at ~constant work.)
//  - Else R14 verbatim: fp16-pair W_hh, single RNE fp16 h, exact fp32
//    x-path, tile order o,f,i,g, dedicated decoder wave (5 waves/block),
//    OOF chunk-parity double buffer, uniform barriers.

#define TLEN 512
#define TCHUNK 64
#define ROWS 8

typedef float    float4_t __attribute__((ext_vector_type(4)));
typedef _Float16 halfx8   __attribute__((ext_vector_type(8)));

#define INV2048 4.8828125e-4f

__device__ __forceinline__ float fexp2(float x){ return __builtin_amdgcn_exp2f(x); }
__device__ __forceinline__ float frcp (float x){ return __builtin_amdgcn_rcpf(x); }
__device__ __forceinline__ float sigm (float x){ return frcp(1.f + fexp2(-1.44269504f*x)); }
__device__ __forceinline__ float tanh_(float x){ return 1.f - 2.f*frcp(1.f + fexp2(2.88539008f*x)); }

__device__ __forceinline__ unsigned short hbits(_Float16 h){
  union { _Float16 h; unsigned short u; } x; x.h = h; return x.u;
}

// setup-only fp16 pair split (lo-plane scaled by 2048 to stay normal)
__device__ __forceinline__ void split8h(const float* v, halfx8& hi, halfx8& lo){
  #pragma unroll
  for (int j = 0; j < 8; j++){
    _Float16 h = (_Float16)v[j];
    hi[j] = h;
    lo[j] = (_Float16)((v[j] - (float)h) * 2048.0f);
  }
}

#define MFMA(a,b,c) __builtin_amdgcn_mfma_f32_16x16x32_f16((a),(b),(c),0,0,0)

// ---- LDS layout ----
// ushort region: h exchange (fp16), double-buffered; rows 8-15 never written
#define HHI 0                 // 2 buf x [16 rows][72]
#define HS_SZ 2304
// float region:
#define XOF 0                 // [8 rows][196] fp32 raw x staging
#define XPK 1568              // [64 t][8 rows][4] packed {x0,x1,x2,0}
#define OOF0 3616             // [8 rows][196] fp32 out staging, chunk-even
#define OOF1 5184             // [8 rows][196] fp32 out staging, chunk-odd
#define LF_SZ 6752

__global__ __launch_bounds__(320, 2)
void LSTMAnomalyDetector_kernel(
    const float* __restrict__ x,     const float* __restrict__ W_ih,
    const float* __restrict__ W_hh,  const float* __restrict__ b_ih,
    const float* __restrict__ b_hh,  const float* __restrict__ W_dec,
    const float* __restrict__ b_dec, float* __restrict__ out)
{
  __shared__ __align__(16) unsigned short HS[HS_SZ];
  __shared__ __align__(16) float          LF[LF_SZ];

  const int tid  = threadIdx.x;
  const int w    = tid >> 6;        // wave 0..4
  const int lane = tid & 63;
  const int q    = lane >> 4;       // quad 0..3
  const int lid  = lane & 15;
  const int b0   = blockIdx.x * ROWS;
  const int cw   = (w & 3)*16 + lid; // recurrence lane's H-column (w<4)
  const bool hiq = (q < 2);
  const int  row0 = (q & 1)*4 + (q >> 1)*2;  // my 2 owned rows: row0, row0+1

  // ---- resident weight fragments (B-operand: B[k=kt*32+q*8+j][n=lid]) ----
  halfx8 Bh[4][2], Bl[4][2];  // W_hh^T fp16 pair; tl = gate type (i,f,g,o)
  halfx8 Dh[2];               // decoder: W_dec^T fp16 single plane (wave 4)
  float  wi[4][3], bsum[4];   // fp32 x-path: W_ih row + (b_ih+b_hh)

  if (w < 4){
    #pragma unroll
    for (int tl = 0; tl < 4; tl++){
      const int g = tl*64 + cw;                 // gate row (W_hh[256][64] row-major)
      #pragma unroll
      for (int kt = 0; kt < 2; kt++){
        const float* p = W_hh + g*64 + kt*32 + q*8;
        float v[8];
        #pragma unroll
        for (int j = 0; j < 8; j++) v[j] = p[j];
        split8h(v, Bh[tl][kt], Bl[tl][kt]);
      }
      wi[tl][0] = W_ih[g*3+0];
      wi[tl][1] = W_ih[g*3+1];
      wi[tl][2] = W_ih[g*3+2];
      bsum[tl]  = b_ih[g] + b_hh[g];
    }
  } else {
    #pragma unroll
    for (int kt = 0; kt < 2; kt++){
      #pragma unroll
      for (int j = 0; j < 8; j++) Dh[kt][j] = (_Float16)0.f;
      if (lid < 3){
        const float* p = W_dec + lid*64 + kt*32 + q*8;
        #pragma unroll
        for (int j = 0; j < 8; j++) Dh[kt][j] = (_Float16)p[j];
      }
    }
  }
  const float bdec = (lid < 3) ? b_dec[lid] : 0.f;

  // ---- state (recurrence waves) ----
  halfx8 ah0 = {}, ah1 = {};                  // h_{t-1} A-frags (fp16), h_{-1}=0
  float creg[2] = {0.f, 0.f};                 // c for rows row0,row0+1 @ col cw
  float4_t xp4[4];                            // fp32 x-part per gate, MFMA seed
                                              // rows q*4+r (masked &7; q>=2 rows
                                              // are garbage C rows, discarded)

  auto loadx = [&](int d){
    #pragma unroll
    for (int r = 0; r < 4; r++){
      const int rr = (q*4 + r) & 7;
      float4_t xv = *(const float4_t*)&LF[XPK + d*32 + rr*4];
      #pragma unroll
      for (int tl = 0; tl < 4; tl++)
        xp4[tl][r] = fmaf(wi[tl][2], xv[2],
                      fmaf(wi[tl][1], xv[1],
                        fmaf(wi[tl][0], xv[0], bsum[tl])));
    }
  };

  // ---- preload + pack x chunk 0 (256 staging threads) ----
  if (w < 4){
    #pragma unroll
    for (int s = 0; s < 2; s++){
      const int f = tid + 256*s;               // 384 float4 = 8 rows x 48
      if (f < 384){
        const int row = f/48; const int off = (f%48)*4;
        float4_t v = *(const float4_t*)(x + (size_t)(b0+row)*1536 + off);
        *(float4_t*)&LF[XOF + row*196 + off] = v;
      }
    }
  }
  __syncthreads();
  if (w < 4){
    #pragma unroll
    for (int s = 0; s < 2; s++){
      const int p = tid + 256*s;               // p = t*8 + row, 0..511
      const float* xr = &LF[XOF + (p & 7)*196 + (p >> 3)*3];
      float4_t v = {xr[0], xr[1], xr[2], 0.f};
      *(float4_t*)&LF[XPK + p*4] = v;
    }
  }
  __syncthreads();
  if (w < 4) loadx(0);

  for (int t = 0; t < TLEN; ++t){
    const int dt = t & (TCHUNK-1);
    const int hb = (t & 1) * 1152;

    if (w < 4){
      // ---- tile o (gate 3) ----
      float4_t c1 = xp4[3];
      c1 = MFMA(ah0, Bh[3][0], c1);
      c1 = MFMA(ah1, Bh[3][1], c1);
      float4_t c2 = {0.f,0.f,0.f,0.f};
      c2 = MFMA(ah0, Bl[3][0], c2);
      c2 = MFMA(ah1, Bl[3][1], c2);
      float4_t to;
      #pragma unroll
      for (int r = 0; r < 4; r++) to[r] = fmaf(c2[r], INV2048, c1[r]);
      const float ro2 = __shfl_xor(to[2], 32, 64);
      const float ro3 = __shfl_xor(to[3], 32, 64);
      const float og0 = sigm(hiq ? to[0] : ro2);
      const float og1 = sigm(hiq ? to[1] : ro3);

      // ---- tile f (gate 1) ----
      c1 = xp4[1];
      c1 = MFMA(ah0, Bh[1][0], c1);
      c1 = MFMA(ah1, Bh[1][1], c1);
      c2 = (float4_t){0.f,0.f,0.f,0.f};
      c2 = MFMA(ah0, Bl[1][0], c2);
      c2 = MFMA(ah1, Bl[1][1], c2);
      float4_t tf;
      #pragma unroll
      for (int r = 0; r < 4; r++) tf[r] = fmaf(c2[r], INV2048, c1[r]);
      const float rf2 = __shfl_xor(tf[2], 32, 64);
      const float rf3 = __shfl_xor(tf[3], 32, 64);
      const float cp0 = sigm(hiq ? tf[0] : rf2) * creg[0];
      const float cp1 = sigm(hiq ? tf[1] : rf3) * creg[1];

      // ---- tile i (gate 0) ----
      c1 = xp4[0];
      c1 = MFMA(ah0, Bh[0][0], c1);
      c1 = MFMA(ah1, Bh[0][1], c1);
      c2 = (float4_t){0.f,0.f,0.f,0.f};
      c2 = MFMA(ah0, Bl[0][0], c2);
      c2 = MFMA(ah1, Bl[0][1], c2);
      float4_t ti;
      #pragma unroll
      for (int r = 0; r < 4; r++) ti[r] = fmaf(c2[r], INV2048, c1[r]);
      const float ri2 = __shfl_xor(ti[2], 32, 64);
      const float ri3 = __shfl_xor(ti[3], 32, 64);
      const float ig0 = sigm(hiq ? ti[0] : ri2);
      const float ig1 = sigm(hiq ? ti[1] : ri3);

      // ---- tile g (gate 2) + tail ----
      c1 = xp4[2];
      c1 = MFMA(ah0, Bh[2][0], c1);
      c1 = MFMA(ah1, Bh[2][1], c1);
      c2 = (float4_t){0.f,0.f,0.f,0.f};
      c2 = MFMA(ah0, Bl[2][0], c2);
      c2 = MFMA(ah1, Bl[2][1], c2);
      float4_t tg;
      #pragma unroll
      for (int r = 0; r < 4; r++) tg[r] = fmaf(c2[r], INV2048, c1[r]);
      const float rg2 = __shfl_xor(tg[2], 32, 64);
      const float rg3 = __shfl_xor(tg[3], 32, 64);
      {
        const float gg = tanh_(hiq ? tg[0] : rg2);
        creg[0] = fmaf(ig0, gg, cp0);
        const float h = og0 * tanh_(creg[0]);
        HS[HHI + hb + row0*72 + cw] = hbits((_Float16)h);
      }
      {
        const float gg = tanh_(hiq ? tg[1] : rg3);
        creg[1] = fmaf(ig1, gg, cp1);
        const float h = og1 * tanh_(creg[1]);
        HS[HHI + hb + (row0+1)*72 + cw] = hbits((_Float16)h);
      }

      // prefetch next step's x-part BEFORE the barrier
      if (dt != TCHUNK-1) loadx(dt+1);
    } else {
      // ---- decoder wave: decode h_{t-1} from the INACTIVE buffer ----
      if (t > 0){
        const int hbp = (1 - (t & 1)) * 1152;
        const unsigned short* ph = &HS[HHI + hbp + lid*72 + q*8];
        halfx8 dh0 = *(const halfx8*)&ph[0];
        halfx8 dh1 = *(const halfx8*)&ph[32];
        float4_t d1 = {0.f,0.f,0.f,0.f};
        d1 = MFMA(dh0, Dh[0], d1);
        d1 = MFMA(dh1, Dh[1], d1);
        if (lid < 3 && q < 2){                 // rows 0-7 real
          const int tp  = t - 1;
          const int oof = OOF0 + ((tp >> 6) & 1) * 1568;
          const int dto = tp & (TCHUNK-1);
          #pragma unroll
          for (int r = 0; r < 4; r++)
            LF[oof + (q*4+r)*196 + dto*3 + lid] = d1[r] + bdec;
        }
      }
    }

    __syncthreads();   // the ONE main barrier per step

    if (w < 4){
      // rebuild A-frags: 2 raw ds_read_b128, zero VALU (rows 8-15 garbage)
      const unsigned short* ph = &HS[HHI + hb + lid*72 + q*8];
      ah0 = *(const halfx8*)&ph[0];
      ah1 = *(const halfx8*)&ph[32];

      // flush previous chunk's OOF once per chunk (disjoint parity buffer)
      if (dt == 1 && t > TCHUNK){
        const int ckf = (t >> 6) - 1;
        const int oof = OOF0 + (ckf & 1) * 1568;
        const int t0  = ckf * TCHUNK;
        #pragma unroll
        for (int s = 0; s < 2; s++){
          const int f = tid + 256*s;
          if (f < 384){
            const int row = f/48; const int off = (f%48)*4;
            float4_t v = *(const float4_t*)&LF[oof + row*196 + off];
            *(float4_t*)(out + (size_t)(b0+row)*1536 + t0*3 + off) = v;
          }
        }
      }
    }

    // chunk boundary: stage+pack next x chunk (uniform barrier structure)
    if (dt == TCHUNK-1){
      if (t + 1 < TLEN){
        if (w < 4){
          #pragma unroll
          for (int s = 0; s < 2; s++){
            const int f = tid + 256*s;
            if (f < 384){
              const int row = f/48; const int off = (f%48)*4;
              float4_t v = *(const float4_t*)(x + (size_t)(b0+row)*1536 + (t+1)*3 + off);
              *(float4_t*)&LF[XOF + row*196 + off] = v;
            }
          }
        }
        __syncthreads();
        if (w < 4){
          #pragma unroll
          for (int s = 0; s < 2; s++){
            const int p = tid + 256*s;
            const float* xr = &LF[XOF + (p & 7)*196 + (p >> 3)*3];
            float4_t v = {xr[0], xr[1], xr[2], 0.f};
            *(float4_t*)&LF[XPK + p*4] = v;
          }
        }
      }
      __syncthreads();
      if (w < 4 && t + 1 < TLEN) loadx(0);
    }
  }

  // ---- epilogue: decode h_511, flush last chunk ----
  if (w == 4){
    const int hbp = ((TLEN-1) & 1) * 1152;     // buffer holding h_511
    const unsigned short* ph = &HS[HHI + hbp + lid*72 + q*8];
    halfx8 dh0 = *(const halfx8*)&ph[0];
    halfx8 dh1 = *(const halfx8*)&ph[32];
    float4_t d1 = {0.f,0.f,0.f,0.f};
    d1 = MFMA(dh0, Dh[0], d1);
    d1 = MFMA(dh1, Dh[1], d1);
    if (lid < 3 && q < 2){
      const int oof = OOF0 + (((TLEN-1) >> 6) & 1) * 1568;
      #pragma unroll
      for (int r = 0; r < 4; r++)
        LF[oof + (q*4+r)*196 + 63*3 + lid] = d1[r] + bdec;
    }
  }
  __syncthreads();
  if (w < 4){
    const int ckf = (TLEN >> 6) - 1;
    const int oof = OOF0 + (ckf & 1) * 1568;
    const int t0  = ckf * TCHUNK;
    #pragma unroll
    for (int s = 0; s < 2; s++){
      const int f = tid + 256*s;
      if (f < 384){
        const int row = f/48; const int off = (f%48)*4;
        float4_t v = *(const float4_t*)&LF[oof + row*196 + off];
        *(float4_t*)(out + (size_t)(b0+row)*1536 + t0*3 + off) = v;
      }
    }
  }
}

extern "C" void kernel_launch(void* const* d_in, const int* in_sizes, int n_in,
                              void* d_out, int out_size, void* d_ws, size_t ws_size,
                              hipStream_t stream)
{
  const float* x     = (const float*)d_in[0];
  const float* W_ih  = (const float*)d_in[1];
  const float* W_hh  = (const float*)d_in[2];
  const float* b_ih  = (const float*)d_in[3];
  const float* b_hh  = (const float*)d_in[4];
  const float* W_dec = (const float*)d_in[5];
  const float* b_dec = (const float*)d_in[6];
  float* out = (float*)d_out;

  const int B = in_sizes[0] / (TLEN * 3);   // 4096
  const int blocks = B / ROWS;              // 512
  hipLaunchKernelGGL(LSTMAnomalyDetector_kernel, dim3(blocks), dim3(320), 0, stream,
                     x, W_ih, W_hh, b_ih, b_hh, W_dec, b_dec, out);
}